// Round 11
// baseline (359.003 us; speedup 1.0000x reference)
//
#include <hip/hip_runtime.h>
#include <hip/hip_bf16.h>

// PolyAttentionBlock: B=16 N=1024 C=768 H=12 D=64. attn = a*s^2+b*s+c (no softmax).
// cvt -> QK/V GEMMs (register-direct, NO LDS, NO barriers, 64x64/wave) -> attn -> proj.

typedef float  f32x4  __attribute__((ext_vector_type(4)));
typedef __bf16 bf16x8 __attribute__((ext_vector_type(8)));
typedef __bf16 bf16x4 __attribute__((ext_vector_type(4)));

#define AS1 __attribute__((address_space(1)))
#define AS3 __attribute__((address_space(3)))

__device__ __forceinline__ void gl16(const void* g, void* l) {
  __builtin_amdgcn_global_load_lds((const AS1 unsigned int*)g, (AS3 unsigned int*)l, 16, 0, 0);
}

// ---------------- f32 -> bf16 cast ----------------
__global__ __launch_bounds__(256) void cvtk(const float* __restrict__ s,
                                            __bf16* __restrict__ d, int n) {
  int i = (blockIdx.x * 256 + threadIdx.x) * 4;
  if (i >= n) return;
  float4 v = *reinterpret_cast<const float4*>(s + i);
  bf16x4 o = { (__bf16)v.x, (__bf16)v.y, (__bf16)v.z, (__bf16)v.w };
  *reinterpret_cast<bf16x4*>(d + i) = o;
}

// ---------------- register-direct GEMM core: 64x64 per wave, no LDS, no barriers ----------------
// Each wave: acc 64x64 (64 VGPR), frags straight from global. Per K-tile (BK=32):
// 4 A-frag + 4 B-frag global_load_dwordx4 (each: 64 lanes = 16 rows x 4x16B = 16 full
// 64B lines, coalesced), 16 MFMA. Explicit a0/b0|a1/b1 register double-buffer (static
// names, rule #20): next-tile loads issue before current-tile MFMAs -> compiler emits
// counted vmcnt (never drains). Waves fully independent -> pure-TLP latency hiding.
// A panels L2-resident per XCD row-chunk (3.1MB<4MB); W fully L2-resident.
// acc[m][n][e]: SWAP -> C[row0+rw+m*16+l15][col0+cw+n*16+lg*4+e]  (e along cols)
//              !SWAP -> C[row0+rw+m*16+lg*4+e][col0+cw+n*16+l15]  (e along rows)
template <bool SWAP>
__device__ __forceinline__ void core_reg(const __bf16* __restrict__ A,
                                         const __bf16* __restrict__ W,
                                         int row0, int col0, int w, int l,
                                         f32x4 (&acc)[4][4]) {
  const int K = 768;
  const int l15 = l & 15, lg = l >> 4;
  const int rw = (w >> 1) * 64, cw = (w & 1) * 64;
  const __bf16* pA[4];
  const __bf16* pB[4];
#pragma unroll
  for (int m = 0; m < 4; ++m)
    pA[m] = A + (size_t)(row0 + rw + m * 16 + l15) * K + lg * 8;
#pragma unroll
  for (int n = 0; n < 4; ++n)
    pB[n] = W + (size_t)(col0 + cw + n * 16 + l15) * K + lg * 8;

#define LOADF(AR, BR, T)                                                       \
  do {                                                                         \
    _Pragma("unroll") for (int m = 0; m < 4; ++m)                              \
        AR[m] = *(const bf16x8*)(pA[m] + (T)*32);                              \
    _Pragma("unroll") for (int n = 0; n < 4; ++n)                              \
        BR[n] = *(const bf16x8*)(pB[n] + (T)*32);                              \
  } while (0)
#define MFMAB(AR, BR)                                                          \
  do {                                                                         \
    __builtin_amdgcn_s_setprio(1);                                             \
    _Pragma("unroll") for (int m = 0; m < 4; ++m)                              \
        _Pragma("unroll") for (int n = 0; n < 4; ++n) {                        \
      if (SWAP)                                                                \
        acc[m][n] = __builtin_amdgcn_mfma_f32_16x16x32_bf16(BR[n], AR[m],      \
                                                            acc[m][n], 0, 0, 0);\
      else                                                                     \
        acc[m][n] = __builtin_amdgcn_mfma_f32_16x16x32_bf16(AR[m], BR[n],      \
                                                            acc[m][n], 0, 0, 0);\
    }                                                                          \
    __builtin_amdgcn_s_setprio(0);                                             \
  } while (0)

  bf16x8 a0[4], b0[4], a1[4], b1[4];
  LOADF(a0, b0, 0);
  for (int t = 0; t < 24; t += 2) {
    LOADF(a1, b1, t + 1);          // prefetch odd tile
    MFMAB(a0, b0);                 // compute even tile (waits only its own loads)
    if (t + 2 < 24) LOADF(a0, b0, t + 2);  // prefetch next even tile
    MFMAB(a1, b1);                 // compute odd tile
  }
#undef LOADF
#undef MFMAB
}

__device__ __forceinline__ int xcd_swz(int fid, int chunk) {
  return (fid & 7) * chunk + (fid >> 3);
}

// ---- QK strips: cols 0..1535 of qkv -> qh/kh[bh][n][64] ----
__global__ __launch_bounds__(256, 3) void gemmQK(
    const __bf16* __restrict__ A, const __bf16* __restrict__ W,
    const float* __restrict__ bias, __bf16* __restrict__ qh,
    __bf16* __restrict__ kh) {
  const int t = threadIdx.x, w = t >> 6, l = t & 63;
  const int l15 = l & 15, lg = l >> 4;
  const int rw = (w >> 1) * 64, cw = (w & 1) * 64;
  const int logical = xcd_swz(blockIdx.x, 192);   // 1536 blocks, nby=12
  const int row0 = (logical / 12) * 128, col0 = (logical % 12) * 128;

  const f32x4 zz = {0.f, 0.f, 0.f, 0.f};
  f32x4 acc[4][4];
#pragma unroll
  for (int m = 0; m < 4; ++m)
#pragma unroll
    for (int n = 0; n < 4; ++n) acc[m][n] = zz;

  core_reg<true>(A, W, row0, col0, w, l, acc);

  f32x4 bv4[4];
#pragma unroll
  for (int n = 0; n < 4; ++n)
    bv4[n] = *(const f32x4*)(bias + col0 + cw + n * 16 + lg * 4);
#pragma unroll
  for (int m = 0; m < 4; ++m) {
    const int row = row0 + rw + m * 16 + l15;
    const int b = row >> 10, nn = row & 1023;
#pragma unroll
    for (int n = 0; n < 4; ++n) {
      const int colb = col0 + cw + n * 16 + lg * 4;
      bf16x4 pk;
#pragma unroll
      for (int e = 0; e < 4; ++e) pk[e] = (__bf16)(acc[m][n][e] + bv4[n][e]);
      if (colb < 768) {
        const int h = colb >> 6, d0 = colb & 63;
        *(bf16x4*)(qh + (((size_t)(b * 12 + h)) << 16) + nn * 64 + d0) = pk;
      } else {
        const int ck = colb - 768, h = ck >> 6, d0 = ck & 63;
        *(bf16x4*)(kh + (((size_t)(b * 12 + h)) << 16) + nn * 64 + d0) = pk;
      }
    }
  }
}

// ---- V strips: W rows 1536.. -> vT[bh][64][1024] ----
__global__ __launch_bounds__(256, 3) void gemmV(
    const __bf16* __restrict__ A, const __bf16* __restrict__ Wv,
    const float* __restrict__ biasv, __bf16* __restrict__ vt) {
  const int t = threadIdx.x, w = t >> 6, l = t & 63;
  const int l15 = l & 15, lg = l >> 4;
  const int rw = (w >> 1) * 64, cw = (w & 1) * 64;
  const int logical = xcd_swz(blockIdx.x, 96);    // 768 blocks, nby=6
  const int row0 = (logical / 6) * 128, col0 = (logical % 6) * 128;

  const f32x4 zz = {0.f, 0.f, 0.f, 0.f};
  f32x4 acc[4][4];
#pragma unroll
  for (int m = 0; m < 4; ++m)
#pragma unroll
    for (int n = 0; n < 4; ++n) acc[m][n] = zz;

  core_reg<false>(A, Wv, row0, col0, w, l, acc);

  float bv[4];
#pragma unroll
  for (int n = 0; n < 4; ++n) bv[n] = biasv[col0 + cw + n * 16 + l15];
#pragma unroll
  for (int m = 0; m < 4; ++m)
#pragma unroll
    for (int n = 0; n < 4; ++n) {
      const int cv = col0 + cw + n * 16 + l15;   // V col 0..767
      const int h = cv >> 6, d = cv & 63;
      const int row = row0 + rw + m * 16 + lg * 4;
      const int b = row >> 10, nn = row & 1023;
      bf16x4 pk;
#pragma unroll
      for (int e = 0; e < 4; ++e) pk[e] = (__bf16)(acc[m][n][e] + bv[n]);
      *(bf16x4*)(vt + (((size_t)(b * 12 + h)) << 16) + (d << 10) + nn) = pk;
    }
}

// ---- proj: f32 packed out ----
__global__ __launch_bounds__(256, 3) void gemmP(
    const __bf16* __restrict__ A, const __bf16* __restrict__ W,
    const float* __restrict__ bias, float* __restrict__ fout) {
  const int t = threadIdx.x, w = t >> 6, l = t & 63;
  const int l15 = l & 15, lg = l >> 4;
  const int rw = (w >> 1) * 64, cw = (w & 1) * 64;
  const int logical = xcd_swz(blockIdx.x, 96);    // 768 blocks, nby=6
  const int row0 = (logical / 6) * 128, col0 = (logical % 6) * 128;

  const f32x4 zz = {0.f, 0.f, 0.f, 0.f};
  f32x4 acc[4][4];
#pragma unroll
  for (int m = 0; m < 4; ++m)
#pragma unroll
    for (int n = 0; n < 4; ++n) acc[m][n] = zz;

  core_reg<true>(A, W, row0, col0, w, l, acc);

  f32x4 bv4[4];
#pragma unroll
  for (int n = 0; n < 4; ++n)
    bv4[n] = *(const f32x4*)(bias + col0 + cw + n * 16 + lg * 4);
#pragma unroll
  for (int m = 0; m < 4; ++m) {
    const int row = row0 + rw + m * 16 + l15;
#pragma unroll
    for (int n = 0; n < 4; ++n) {
      const int colb = col0 + cw + n * 16 + lg * 4;
      f32x4 v;
#pragma unroll
      for (int e = 0; e < 4; ++e) v[e] = acc[m][n][e] + bv4[n][e];
      *(f32x4*)(fout + (size_t)row * 768 + colb) = v;
    }
  }
}

// ---------------- fused poly attention (unchanged from r10) ----------------
__global__ __launch_bounds__(256, 3) void attnk(const __bf16* __restrict__ qh,
                                                const __bf16* __restrict__ kh,
                                                const __bf16* __restrict__ vT,
                                                __bf16* __restrict__ o,
                                                const float* __restrict__ poly) {
  __shared__ char lkv[2][16384];   // [buf]: K @ 0 ([m][d=64] swz), V @ 8192 ([d][m=64] swz)
  __shared__ __bf16 lP[128 * 64];  // [q][m=64]; wave w owns rows w*32..+31
  const int t = threadIdx.x, w = t >> 6, l = t & 63;
  const int l15 = l & 15, lg = l >> 4;

  const int fid = blockIdx.y * 8 + blockIdx.x;       // 0..1535
  const int logical = (fid & 7) * 192 + (fid >> 3);
  const int bh = logical >> 3, q0 = (logical & 7) * 128;
  const float pa = poly[0], pb = poly[1], pc = poly[2];
  const f32x4 zz = {0.f, 0.f, 0.f, 0.f};
  const size_t bhoff = ((size_t)bh) << 16;

  bf16x8 qf[2][2];
#pragma unroll
  for (int a = 0; a < 2; ++a)
#pragma unroll
    for (int kk = 0; kk < 2; ++kk)
      qf[a][kk] = *(const bf16x8*)(qh + bhoff + (q0 + w * 32 + 16 * a + l15) * 64 +
                                   kk * 32 + lg * 8);

  f32x4 oacc[2][4];
#pragma unroll
  for (int mf = 0; mf < 2; ++mf)
#pragma unroll
    for (int n = 0; n < 4; ++n) oacc[mf][n] = zz;

  const int srow = l >> 3;
  const int sunit = (l & 7) ^ (srow & 7);

#define STAGE(MT, BUF)                                                              \
  do {                                                                              \
    const int m0_ = (MT)*64;                                                        \
    _Pragma("unroll") for (int c = 0; c < 2; ++c) {                                 \
      const int s_ = w * 2 + c;                                                     \
      gl16(kh + bhoff + (m0_ + 8 * s_ + srow) * 64 + (sunit << 3),                  \
           lkv[BUF] + s_ * 1024);                                                   \
      gl16(vT + bhoff + (8 * s_ + srow) * 1024 + m0_ + (sunit << 3),                \
           lkv[BUF] + 8192 + s_ * 1024);                                            \
    }                                                                               \
  } while (0)

  STAGE(0, 0);
  __syncthreads();

  for (int mt = 0; mt < 16; ++mt) {
    const int cur = mt & 1;
    if (mt + 1 < 16) STAGE(mt + 1, cur ^ 1);

    // S^T = K Q^T
    f32x4 sacc[2][4];
#pragma unroll
    for (int kk = 0; kk < 2; ++kk) {
      bf16x8 kf[4];
#pragma unroll
      for (int c = 0; c < 4; ++c) {
        int r = 16 * c + l15;
        kf[c] = *(const bf16x8*)(lkv[cur] + r * 128 + (((kk * 4 + lg) ^ (r & 7)) << 4));
      }
      __builtin_amdgcn_s_setprio(1);
#pragma unroll
      for (int a = 0; a < 2; ++a)
#pragma unroll
        for (int c = 0; c < 4; ++c)
          sacc[a][c] = __builtin_amdgcn_mfma_f32_16x16x32_bf16(
              kf[c], qf[a][kk], kk == 0 ? zz : sacc[a][c], 0, 0, 0);
      __builtin_amdgcn_s_setprio(0);
    }

    // poly -> packed bf16x4 ds_write into own wave's lP rows
#pragma unroll
    for (int a = 0; a < 2; ++a)
#pragma unroll
      for (int c = 0; c < 4; ++c) {
        int q = w * 32 + 16 * a + l15;
        int mb2 = 32 * c + 8 * lg;
        bf16x4 pk;
#pragma unroll
        for (int e = 0; e < 4; ++e) {
          float s = sacc[a][c][e] * 0.125f;
          float p = (pa * s + pb) * s + pc;
          pk[e] = (__bf16)p;
        }
        *(bf16x4*)((char*)lP + q * 128 + (mb2 ^ ((q & 7) << 4))) = pk;
      }

    // O^T += V P^T (swapped: O^T frags, e runs along d)
#pragma unroll
    for (int kk = 0; kk < 2; ++kk) {
      bf16x8 vf[4];
#pragma unroll
      for (int nf = 0; nf < 4; ++nf) {
        int d = 16 * nf + l15;
        vf[nf] = *(const bf16x8*)(lkv[cur] + 8192 + d * 128 + (((kk * 4 + lg) ^ (d & 7)) << 4));
      }
      bf16x8 pf[2];
#pragma unroll
      for (int mf = 0; mf < 2; ++mf) {
        int q = w * 32 + 16 * mf + l15;
        pf[mf] = *(const bf16x8*)((const char*)lP + q * 128 + (((kk * 4 + lg) ^ (q & 7)) << 4));
      }
      __builtin_amdgcn_s_setprio(1);
#pragma unroll
      for (int mf = 0; mf < 2; ++mf)
#pragma unroll
        for (int nf = 0; nf < 4; ++nf)
          oacc[mf][nf] = __builtin_amdgcn_mfma_f32_16x16x32_bf16(vf[nf], pf[mf], oacc[mf][nf], 0, 0, 0);
      __builtin_amdgcn_s_setprio(0);
    }
    __syncthreads();
  }
#undef STAGE

  const int b = bh / 12, h = bh - b * 12;
#pragma unroll
  for (int mf = 0; mf < 2; ++mf) {
    const int q = q0 + w * 32 + 16 * mf + l15;
#pragma unroll
    for (int nf = 0; nf < 4; ++nf) {
      bf16x4 pk;
#pragma unroll
      for (int e = 0; e < 4; ++e) pk[e] = (__bf16)oacc[mf][nf][e];
      *(bf16x4*)(o + (size_t)(b * 1024 + q) * 768 + h * 64 + 16 * nf + 4 * lg) = pk;
    }
  }
}

// ---------------- launch ----------------
extern "C" void kernel_launch(void* const* d_in, const int* in_sizes, int n_in,
                              void* d_out, int out_size, void* d_ws, size_t ws_size,
                              hipStream_t stream) {
  const float* x      = (const float*)d_in[0];
  const float* w_qkv  = (const float*)d_in[1];
  const float* b_qkv  = (const float*)d_in[2];
  const float* w_proj = (const float*)d_in[3];
  const float* b_proj = (const float*)d_in[4];
  const float* poly   = (const float*)d_in[5];

  char* ws = (char*)d_ws;
  __bf16* xb     = (__bf16*)(ws);                 // 16384x768   = 25165824 B
  __bf16* wqkvb  = (__bf16*)(ws + 25165824);      // 2304x768    =  3538944 B
  __bf16* wprojb = (__bf16*)(ws + 28704768);      // 768x768     =  1179648 B
  __bf16* qh     = (__bf16*)(ws + 29884416);      // 192x1024x64 = 25165824 B
  __bf16* kh     = (__bf16*)(ws + 55050240);      // 192x1024x64 = 25165824 B
  __bf16* vtb    = (__bf16*)(ws + 80216064);      // 192x64x1024 = 25165824 B
  __bf16* ob     = (__bf16*)(ws + 105381888);     // 16384x768   = 25165824 B

  cvtk<<<12582912 / 1024, 256, 0, stream>>>(x, xb, 12582912);
  cvtk<<<1769472 / 1024, 256, 0, stream>>>(w_qkv, wqkvb, 1769472);
  cvtk<<<589824 / 1024, 256, 0, stream>>>(w_proj, wprojb, 589824);

  gemmQK<<<1536, 256, 0, stream>>>(xb, wqkvb, b_qkv, qh, kh);
  gemmV<<<768, 256, 0, stream>>>(xb, wqkvb + (size_t)1536 * 768, b_qkv + 1536, vtb);
  attnk<<<dim3(8, 192), 256, 0, stream>>>(qh, kh, vtb, ob, poly);
  gemmP<<<768, 256, 0, stream>>>(ob, wprojb, b_proj, (float*)d_out);
}

// Round 12
// 181.428 us; speedup vs baseline: 1.9788x; 1.9788x over previous
//
#include <hip/hip_runtime.h>
#include <hip/hip_bf16.h>

// PolyAttentionBlock: B=16 N=1024 C=768 H=12 D=64. attn = a*s^2+b*s+c (no softmax).
// cvt(f32->bf16) -> QKV GEMM (256^2 8-phase, V written transposed) -> fused poly-attn -> proj GEMM.
// ROUND 12: verbatim restore of the round-4 configuration (best measured: 181.3 us).

typedef float  f32x4  __attribute__((ext_vector_type(4)));
typedef __bf16 bf16x8 __attribute__((ext_vector_type(8)));
typedef __bf16 bf16x4 __attribute__((ext_vector_type(4)));

#define AS1 __attribute__((address_space(1)))
#define AS3 __attribute__((address_space(3)))

__device__ __forceinline__ void gl16(const void* g, void* l) {
  // async global->LDS, 16B/lane; LDS dest = wave-uniform base + lane*16
  __builtin_amdgcn_global_load_lds((const AS1 unsigned int*)g, (AS3 unsigned int*)l, 16, 0, 0);
}

// ---------------- f32 -> bf16 cast ----------------
__global__ __launch_bounds__(256) void cvtk(const float* __restrict__ s,
                                            __bf16* __restrict__ d, int n) {
  int i = (blockIdx.x * 256 + threadIdx.x) * 4;
  if (i >= n) return;
  float4 v = *reinterpret_cast<const float4*>(s + i);
  bf16x4 o = { (__bf16)v.x, (__bf16)v.y, (__bf16)v.z, (__bf16)v.w };
  *reinterpret_cast<bf16x4*>(d + i) = o;
}

// ---------------- 256x256 8-phase GEMM: out[M,Nn] = A[M,K] @ W[Nn,K]^T + bias ----------------
// 512 thr = 8 waves (2M x 4N), BK=64, LDS 128KB (2 dbuf x (A 32KB + B 32KB)), XOR-swizzled.
// Per iteration: 8 phases, 2 K-tiles. Counted vmcnt(6) at phases 4/8 only (T3+T4); T5 setprio.
// Phase skeleton per m201 template: {ds_read + stage} ; s_barrier ; lgkmcnt(0) ; MFMA ; s_barrier.
// NO sched_barrier(0) (m141: order-pinning regresses 874->510 TF).
// MODE 0: bf16 out; col>=1536 (V part) stored transposed to vout[B,H,64,1024]. MODE 1: f32 out.
template <int MODE>
__global__ __launch_bounds__(512, 2) void gemm256k(
    const __bf16* __restrict__ A, const __bf16* __restrict__ W,
    const float* __restrict__ bias, void* __restrict__ outp,
    __bf16* __restrict__ vout, int K, int nby, int chunk, int ldo) {
  __shared__ char lds[131072];  // buf b: A at b*65536, B at b*65536+32768; rows 128B
  const int t = threadIdx.x, w = t >> 6, l = t & 63;
  const int l15 = l & 15, lg = l >> 4;
  const int wm = w >> 2, wn = w & 3;       // wave grid 2x4; wave tile 128r x 64c
  const int lr = l >> 3, sw = l & 7;       // staging row-in-8, phys 16B-unit

  // bijective XCD-chunked swizzle (nblocks % 8 == 0); row-major chunks:
  // each XCD gets (chunk/nby) consecutive row-tiles x ALL col-tiles -> A panels
  // fetched once per XCD, W resident in L2.
  const int fid = blockIdx.x;
  const int logical = (fid & 7) * chunk + (fid >> 3);
  const int bx = logical / nby, by = logical % nby;
  const int row0 = bx * 256, col0 = by * 256;

  const f32x4 zz = {0.f, 0.f, 0.f, 0.f};
  f32x4 acc[8][4];
#pragma unroll
  for (int m = 0; m < 8; ++m)
#pragma unroll
    for (int n = 0; n < 4; ++n) acc[m][n] = zz;
  bf16x8 af[2][2], bfr[4][2];

// stage one A-quarter (rows {Q*32..+31} u {128+Q*32..+31}) of K-tile KT into buf BUF
#define STA(BUF, Q, KT)                                                               \
  do {                                                                                \
    const int rr_ = (w < 4 ? (Q)*32 + w * 8 : 128 + (Q)*32 + (w & 3) * 8) + lr;       \
    gl16(A + (size_t)(row0 + rr_) * K + (KT)*64 + ((sw ^ (rr_ & 7)) << 3),            \
         lds + (BUF)*65536 +                                                          \
             (w < 4 ? (Q)*4096 + w * 1024 : 16384 + (Q)*4096 + (w & 3) * 1024));      \
  } while (0)
// stage B 64-row chunk C of K-tile KT into buf BUF
#define STB(BUF, C, KT)                                                               \
  do {                                                                                \
    const int rr_ = (C)*64 + w * 8 + lr;                                              \
    gl16(W + (size_t)(col0 + rr_) * K + (KT)*64 + ((sw ^ (rr_ & 7)) << 3),            \
         lds + (BUF)*65536 + 32768 + (C)*8192 + w * 1024);                            \
  } while (0)
// ds-read A-frags for m-reps {2*MQ, 2*MQ+1}, both k-frags
#define RDA(BUF, MQ)                                                                  \
  do {                                                                                \
    _Pragma("unroll") for (int j = 0; j < 2; ++j) {                                   \
      const int ra_ = wm * 128 + (2 * (MQ) + j) * 16 + l15;                           \
      _Pragma("unroll") for (int kf = 0; kf < 2; ++kf)                                \
          af[j][kf] = *(const bf16x8*)((const char*)lds + (BUF)*65536 + ra_ * 128 +   \
                                       (((kf * 4 + lg) ^ (ra_ & 7)) << 4));           \
    }                                                                                 \
  } while (0)
// ds-read all B-frags (held in regs across 4 phases)
#define RDB(BUF)                                                                      \
  do {                                                                                \
    _Pragma("unroll") for (int n = 0; n < 4; ++n) {                                   \
      const int rb_ = wn * 64 + n * 16 + l15;                                         \
      _Pragma("unroll") for (int kf = 0; kf < 2; ++kf)                                \
          bfr[n][kf] = *(const bf16x8*)((const char*)lds + (BUF)*65536 + 32768 +      \
                                        rb_ * 128 + (((kf * 4 + lg) ^ (rb_ & 7)) << 4)); \
    }                                                                                 \
  } while (0)
#define MF16(MQ)                                                                      \
  do {                                                                                \
    __builtin_amdgcn_s_setprio(1);                                                    \
    _Pragma("unroll") for (int j = 0; j < 2; ++j)                                     \
        _Pragma("unroll") for (int n = 0; n < 4; ++n)                                 \
            _Pragma("unroll") for (int kf = 0; kf < 2; ++kf)                          \
                acc[2 * (MQ) + j][n] = __builtin_amdgcn_mfma_f32_16x16x32_bf16(       \
                    af[j][kf], bfr[n][kf], acc[2 * (MQ) + j][n], 0, 0, 0);            \
    __builtin_amdgcn_s_setprio(0);                                                    \
  } while (0)
#define BAR1 __builtin_amdgcn_s_barrier(); asm volatile("s_waitcnt lgkmcnt(0)" ::: "memory")
#define BAR2 __builtin_amdgcn_s_barrier()

  // prologue: K-tile 0 -> buf0 (8 calls), K-tile 1 -> buf1 first 6 calls
  STA(0, 0, 0); STB(0, 0, 0); STA(0, 1, 0); STB(0, 1, 0);
  STA(0, 2, 0); STB(0, 2, 0); STA(0, 3, 0); STB(0, 3, 0);
  STA(1, 0, 1); STB(1, 0, 1); STA(1, 1, 1); STB(1, 1, 1); STA(1, 2, 1); STB(1, 2, 1);
  asm volatile("s_waitcnt vmcnt(6)" ::: "memory");
  BAR2;

  const int NI = K >> 7;  // iterations (2 K-tiles each)
  for (int i = 0; i < NI; ++i) {
    const bool last = (i == NI - 1);
    const int t1 = 2 * i + 1, t2 = 2 * i + 2, t3 = 2 * i + 3;
    // ph1: compute buf0 mq0; stage buf1's last calls of K-tile t1
    RDA(0, 0); RDB(0);
    STA(1, 3, t1); STB(1, 3, t1);
    BAR1; MF16(0); BAR2;
    // ph2
    RDA(0, 1);
    if (!last) { STA(0, 0, t2); STB(0, 0, t2); }
    BAR1; MF16(1); BAR2;
    // ph3
    RDA(0, 2);
    if (!last) { STA(0, 1, t2); STB(0, 1, t2); }
    BAR1; MF16(2); BAR2;
    // ph4 + gate
    RDA(0, 3);
    if (!last) { STA(0, 2, t2); STB(0, 2, t2); }
    if (last) { asm volatile("s_waitcnt vmcnt(0)" ::: "memory"); }
    else      { asm volatile("s_waitcnt vmcnt(6)" ::: "memory"); }
    BAR1; MF16(3); BAR2;
    // ph5: compute buf1 mq0
    RDA(1, 0); RDB(1);
    if (!last) { STA(0, 3, t2); STB(0, 3, t2); }
    BAR1; MF16(0); BAR2;
    // ph6
    RDA(1, 1);
    if (!last) { STA(1, 0, t3); STB(1, 0, t3); }
    BAR1; MF16(1); BAR2;
    // ph7
    RDA(1, 2);
    if (!last) { STA(1, 1, t3); STB(1, 1, t3); }
    BAR1; MF16(2); BAR2;
    // ph8 + gate
    RDA(1, 3);
    if (!last) { STA(1, 2, t3); STB(1, 2, t3); }
    if (!last) { asm volatile("s_waitcnt vmcnt(6)" ::: "memory"); }
    BAR1; MF16(3); BAR2;
  }

  // epilogue
  float bv[4];
#pragma unroll
  for (int n = 0; n < 4; ++n) bv[n] = bias[col0 + wn * 64 + n * 16 + l15];

  if (MODE == 0 && col0 >= 1536) {
    // V columns -> vout[B,H,64,1024] transposed; e-direction is contiguous in vout
#pragma unroll
    for (int m = 0; m < 8; ++m)
#pragma unroll
      for (int n = 0; n < 4; ++n) {
        const int cv = col0 + wn * 64 + n * 16 + l15 - 1536;
        const int h = cv >> 6, d = cv & 63;
        const int row = row0 + wm * 128 + m * 16 + lg * 4;
        const int b = row >> 10, nn = row & 1023;
        bf16x4 pk;
#pragma unroll
        for (int e = 0; e < 4; ++e) pk[e] = (__bf16)(acc[m][n][e] + bv[n]);
        *(bf16x4*)(vout + (((size_t)(b * 12 + h)) << 16) + (d << 10) + nn) = pk;
      }
  } else {
#pragma unroll
    for (int m = 0; m < 8; ++m)
#pragma unroll
      for (int n = 0; n < 4; ++n)
#pragma unroll
        for (int e = 0; e < 4; ++e) {
          const int r = row0 + wm * 128 + m * 16 + lg * 4 + e;
          const int cc = col0 + wn * 64 + n * 16 + l15;
          const float v = acc[m][n][e] + bv[n];
          if (MODE == 0) ((__bf16*)outp)[(size_t)r * ldo + cc] = (__bf16)v;
          else           ((float*)outp)[(size_t)r * ldo + cc] = v;
        }
  }
#undef STA
#undef STB
#undef RDA
#undef RDB
#undef MF16
#undef BAR1
#undef BAR2
}

// ---------------- fused poly attention ----------------
// grid 1536 blocks (XCD-chunked swizzle), 256 thr = 4 waves; KVBLK=64, 16 tiles.
// Swapped QK^T -> per-thread consecutive-m P -> packed bf16x4 ds_write into per-wave lP.
__global__ __launch_bounds__(256, 3) void attnk(const __bf16* __restrict__ qkv,
                                                const __bf16* __restrict__ vT,
                                                __bf16* __restrict__ o,
                                                const float* __restrict__ poly) {
  __shared__ __bf16 lK[64 * 64];   // 8KB  [m][d=64], 128B rows, XOR-swizzled
  __shared__ __bf16 lV[64 * 64];   // 8KB  [d][m=64], 128B rows, XOR-swizzled
  __shared__ __bf16 lP[128 * 64];  // 16KB [q][m=64], 128B rows, XOR-swizzled; wave w owns rows w*32..+31
  const int t = threadIdx.x, w = t >> 6, l = t & 63;
  const int l15 = l & 15, lg = l >> 4;

  const int fid = blockIdx.y * 8 + blockIdx.x;       // 0..1535
  const int logical = (fid & 7) * 192 + (fid >> 3);
  const int bh = logical >> 3, q0 = (logical & 7) * 128;
  const int b = bh / 12, h = bh - b * 12;
  const float pa = poly[0], pb = poly[1], pc = poly[2];
  const f32x4 zz = {0.f, 0.f, 0.f, 0.f};

  bf16x8 qf[2][2];
#pragma unroll
  for (int a = 0; a < 2; ++a)
#pragma unroll
    for (int kk = 0; kk < 2; ++kk)
      qf[a][kk] = *(const bf16x8*)(qkv + (size_t)(b * 1024 + q0 + w * 32 + 16 * a + l15) * 2304 +
                                   h * 64 + kk * 32 + lg * 8);

  f32x4 oacc[2][4];
#pragma unroll
  for (int mf = 0; mf < 2; ++mf)
#pragma unroll
    for (int n = 0; n < 4; ++n) oacc[mf][n] = zz;

  const int srow = l >> 3;
  const int sunit = (l & 7) ^ (srow & 7);
  for (int mt = 0; mt < 16; ++mt) {
    const int m0 = mt * 64;
#pragma unroll
    for (int c = 0; c < 2; ++c) {
      int s = w * 2 + c;
      gl16(qkv + (size_t)(b * 1024 + m0 + 8 * s + srow) * 2304 + 768 + h * 64 + (sunit << 3),
           (char*)lK + s * 1024);
    }
#pragma unroll
    for (int c = 0; c < 2; ++c) {
      int s = w * 2 + c;
      gl16(vT + (size_t)(bh * 64 + 8 * s + srow) * 1024 + m0 + (sunit << 3),
           (char*)lV + s * 1024);
    }
    __syncthreads();

    // S^T = K Q^T
    f32x4 sacc[2][4];
#pragma unroll
    for (int kk = 0; kk < 2; ++kk) {
      bf16x8 kf[4];
#pragma unroll
      for (int c = 0; c < 4; ++c) {
        int r = 16 * c + l15;
        kf[c] = *(const bf16x8*)((const char*)lK + r * 128 + (((kk * 4 + lg) ^ (r & 7)) << 4));
      }
      __builtin_amdgcn_s_setprio(1);
#pragma unroll
      for (int a = 0; a < 2; ++a)
#pragma unroll
        for (int c = 0; c < 4; ++c)
          sacc[a][c] = __builtin_amdgcn_mfma_f32_16x16x32_bf16(
              kf[c], qf[a][kk], kk == 0 ? zz : sacc[a][c], 0, 0, 0);
      __builtin_amdgcn_s_setprio(0);
    }

    // poly -> packed bf16x4 -> one ds_write_b64 per fragment
#pragma unroll
    for (int a = 0; a < 2; ++a)
#pragma unroll
      for (int c = 0; c < 4; ++c) {
        int q = w * 32 + 16 * a + l15;
        int mb2 = 32 * c + 8 * lg;
        bf16x4 pk;
#pragma unroll
        for (int e = 0; e < 4; ++e) {
          float s = sacc[a][c][e] * 0.125f;
          float p = (pa * s + pb) * s + pc;
          pk[e] = (__bf16)p;
        }
        *(bf16x4*)((char*)lP + q * 128 + (mb2 ^ ((q & 7) << 4))) = pk;
      }

    // O += P @ V
#pragma unroll
    for (int kk = 0; kk < 2; ++kk) {
      bf16x8 vf[4];
#pragma unroll
      for (int nf = 0; nf < 4; ++nf) {
        int d = 16 * nf + l15;
        vf[nf] = *(const bf16x8*)((const char*)lV + d * 128 + (((kk * 4 + lg) ^ (d & 7)) << 4));
      }
      bf16x8 pf[2];
#pragma unroll
      for (int mf = 0; mf < 2; ++mf) {
        int q = w * 32 + 16 * mf + l15;
        pf[mf] = *(const bf16x8*)((const char*)lP + q * 128 + (((kk * 4 + lg) ^ (q & 7)) << 4));
      }
      __builtin_amdgcn_s_setprio(1);
#pragma unroll
      for (int mf = 0; mf < 2; ++mf)
#pragma unroll
        for (int nf = 0; nf < 4; ++nf)
          oacc[mf][nf] = __builtin_amdgcn_mfma_f32_16x16x32_bf16(pf[mf], vf[nf], oacc[mf][nf], 0, 0, 0);
      __builtin_amdgcn_s_setprio(0);
    }
    __syncthreads();
  }

#pragma unroll
  for (int mf = 0; mf < 2; ++mf)
#pragma unroll
    for (int nf = 0; nf < 4; ++nf)
#pragma unroll
      for (int e = 0; e < 4; ++e) {
        int row = q0 + w * 32 + 16 * mf + 4 * lg + e;
        int d = 16 * nf + l15;
        o[(size_t)(b * 1024 + row) * 768 + h * 64 + d] = (__bf16)oacc[mf][nf][e];
      }
}

// ---------------- launch ----------------
extern "C" void kernel_launch(void* const* d_in, const int* in_sizes, int n_in,
                              void* d_out, int out_size, void* d_ws, size_t ws_size,
                              hipStream_t stream) {
  const float* x      = (const float*)d_in[0];  // [16,1024,768]
  const float* w_qkv  = (const float*)d_in[1];  // [2304,768]
  const float* b_qkv  = (const float*)d_in[2];  // [2304]
  const float* w_proj = (const float*)d_in[3];  // [768,768]
  const float* b_proj = (const float*)d_in[4];  // [768]
  const float* poly   = (const float*)d_in[5];  // [3]

  char* ws = (char*)d_ws;
  __bf16* xb     = (__bf16*)(ws);                 // 16384x768   = 25165824 B
  __bf16* wqkvb  = (__bf16*)(ws + 25165824);      // 2304x768    =  3538944 B
  __bf16* wprojb = (__bf16*)(ws + 28704768);      // 768x768     =  1179648 B
  __bf16* qkvb   = (__bf16*)(ws + 29884416);      // 16384x2304  = 75497472 B
  __bf16* vtb    = (__bf16*)(ws + 105381888);     // 192x64x1024 = 25165824 B
  __bf16* ob     = (__bf16*)(ws + 130547712);     // 16384x768   = 25165824 B

  cvtk<<<12582912 / 1024, 256, 0, stream>>>(x, xb, 12582912);
  cvtk<<<1769472 / 1024, 256, 0, stream>>>(w_qkv, wqkvb, 1769472);
  cvtk<<<589824 / 1024, 256, 0, stream>>>(w_proj, wprojb, 589824);

  // QKV: M=16384 (64 tiles) x N=2304 (9 tiles) = 576 blocks; V cols -> vtb transposed
  gemm256k<0><<<576, 512, 0, stream>>>(xb, wqkvb, b_qkv, qkvb, vtb, 768, 9, 72, 2304);
  attnk<<<dim3(8, 192), 256, 0, stream>>>(qkvb, vtb, ob, poly);
  // proj: M=16384 x N=768 (3 tiles) = 192 blocks
  gemm256k<1><<<192, 512, 0, stream>>>(ob, wprojb, b_proj, d_out, nullptr, 768, 3, 24, 768);
}